// Round 12
// baseline (363.320 us; speedup 1.0000x reference)
//
#include <hip/hip_runtime.h>
#include <hip/hip_bf16.h>

#define GNN_N 50000
#define GNN_E 600000

typedef unsigned int uint;
typedef unsigned short ushort;
using short8 = __attribute__((ext_vector_type(8))) short;
using f32x4  = __attribute__((ext_vector_type(4))) float;

__device__ __forceinline__ float leaky02(float x) { return x > 0.f ? x : 0.2f * x; }
__device__ __forceinline__ ushort f2b(float f) {  // RNE float->bf16
    uint u = __float_as_uint(f);
    return (ushort)((u + 0x7fffu + ((u >> 16) & 1u)) >> 16);
}
__device__ __forceinline__ float b2f(ushort b) { return __uint_as_float(((uint)b) << 16); }
__device__ __forceinline__ float blo(uint u) { return __uint_as_float(u << 16); }
__device__ __forceinline__ float bhi(uint u) { return __uint_as_float(u & 0xffff0000u); }

// ---------------- CSR build (fully deterministic) ----------------
__global__ void gnn_hist(const int* __restrict__ dst, int* __restrict__ cnt, int e) {
    int i = blockIdx.x * blockDim.x + threadIdx.x;
    if (i < e) atomicAdd(&cnt[dst[i]], 1);
}
__global__ void gnn_scan1(const int* __restrict__ cnt, int* __restrict__ row_ptr,
                          int* __restrict__ blksum, int n) {
    __shared__ int sh[256];
    int tid = threadIdx.x;
    int base = blockIdx.x * 1024 + tid * 4;
    int v0 = (base + 0 < n) ? cnt[base + 0] : 0;
    int v1 = (base + 1 < n) ? cnt[base + 1] : 0;
    int v2 = (base + 2 < n) ? cnt[base + 2] : 0;
    int v3 = (base + 3 < n) ? cnt[base + 3] : 0;
    int tsum = v0 + v1 + v2 + v3;
    sh[tid] = tsum;
    __syncthreads();
    for (int off = 1; off < 256; off <<= 1) {
        int t = (tid >= off) ? sh[tid - off] : 0;
        __syncthreads();
        sh[tid] += t;
        __syncthreads();
    }
    int excl = sh[tid] - tsum;
    if (base + 0 < n) row_ptr[base + 0] = excl; excl += v0;
    if (base + 1 < n) row_ptr[base + 1] = excl; excl += v1;
    if (base + 2 < n) row_ptr[base + 2] = excl; excl += v2;
    if (base + 3 < n) row_ptr[base + 3] = excl;
    if (tid == 255) blksum[blockIdx.x] = sh[255];
}
__global__ void gnn_scan2(int* blksum, int nblk, int* row_ptr_end, int total) {
    if (threadIdx.x == 0 && blockIdx.x == 0) {
        int run = 0;
        for (int b = 0; b < nblk; ++b) { int t = blksum[b]; blksum[b] = run; run += t; }
        *row_ptr_end = total;
    }
}
__global__ void gnn_scan3(int* row_ptr, const int* __restrict__ blksum, int n) {
    int i = blockIdx.x * blockDim.x + threadIdx.x;
    if (i < n) row_ptr[i] += blksum[i >> 10];
}
// place edge indices into rows (slot order arbitrary; canonicalized by gnn_sortdeg)
__global__ void gnn_scatter_idx(const int* __restrict__ dst, const int* __restrict__ row_ptr,
                                int* __restrict__ fill, int* __restrict__ tord, int e) {
    int i = blockIdx.x * blockDim.x + threadIdx.x;
    if (i >= e) return;
    int d = dst[i];
    int pos = row_ptr[d] + atomicAdd(&fill[d], 1);
    tord[pos] = i;
}
// one thread per node: insertion-sort row's edge indices ascending (canonical order),
// then weighted degree in sorted order (deterministic fp32 sum) -> dinv.
__global__ void gnn_sortdeg(const float* __restrict__ ew, int* __restrict__ tord,
                            const int* __restrict__ row_ptr, float* __restrict__ dinv, int n) {
    int v = blockIdx.x * blockDim.x + threadIdx.x;
    if (v >= n) return;
    int beg = row_ptr[v], end = row_ptr[v + 1];
    int d = end - beg;
    if (d <= 64) {
        int buf[64];
        for (int i = 0; i < d; ++i) buf[i] = tord[beg + i];
        for (int i = 1; i < d; ++i) {
            int key = buf[i];
            int k = i - 1;
            while (k >= 0 && buf[k] > key) { buf[k + 1] = buf[k]; --k; }
            buf[k + 1] = key;
        }
        float s = 1.f;  // self-loop weight
        for (int i = 0; i < d; ++i) { tord[beg + i] = buf[i]; s += ew[buf[i]]; }
        dinv[v] = rsqrtf(s);
    } else {  // rare fallback: in-place global insertion sort
        for (int i = beg + 1; i < end; ++i) {
            int key = tord[i];
            int k = i - 1;
            while (k >= beg && tord[k] > key) { tord[k + 1] = tord[k]; --k; }
            tord[k + 1] = key;
        }
        float s = 1.f;
        for (int i = beg; i < end; ++i) s += ew[tord[i]];
        dinv[v] = rsqrtf(s);
    }
}
// finalize CSR payload from sorted order (deterministic)
__global__ void gnn_edgefin(const int* __restrict__ src, const int* __restrict__ dst,
                            const float* __restrict__ ew, const float* __restrict__ dinv,
                            const int* __restrict__ tord, int* __restrict__ esrc,
                            float* __restrict__ ecw, int e) {
    int pos = blockIdx.x * blockDim.x + threadIdx.x;
    if (pos >= e) return;
    int i = tord[pos];
    int s = src[i];
    esrc[pos] = s;
    ecw[pos] = dinv[s] * ew[i] * dinv[dst[i]];
}

// ---------------- fused prep: weight transposes/folds ----------------
__global__ void gnn_prep(const float* __restrict__ gc1_w, const float* __restrict__ gat_w,
                         const float* __restrict__ gc2_w, const float* __restrict__ att_src,
                         const float* __restrict__ att_dst, ushort* __restrict__ w1t,
                         ushort* __restrict__ w2s_t, ushort* __restrict__ w3t,
                         float* __restrict__ wa_t) {
    int t = blockIdx.x * 256 + threadIdx.x;
    if (t < 32768) {                       // gc1_w [256][128] -> w1t[128][256]
        int k = t >> 7, n = t & 127;
        w1t[n * 256 + k] = f2b(gc1_w[t]);
        return;
    }
    t -= 32768;
    if (t < 65536) {                       // w2s_t[c][h*128+k] = gat_w[k][h*64+c]/8
        int c = t >> 10, r = t & 1023;
        int h = r >> 7, k = r & 127;
        w2s_t[t] = f2b(0.125f * gat_w[(size_t)k * 512 + h * 64 + c]);
        return;
    }
    t -= 65536;
    if (t < 4096) {                        // gc2_w [64][64] -> w3t[64][64]
        int k = t >> 6, n = t & 63;
        w3t[n * 64 + k] = f2b(gc2_w[t]);
        return;
    }
    t -= 4096;
    if (t < 2048) {                        // wa_t[16][128]: fold att into weight space
        int j = t >> 7, k = t & 127;
        int h = j & 7;
        const float* av = (j < 8) ? att_src : att_dst;
        float s = 0.f;
        for (int c = 0; c < 64; ++c) s += gat_w[(size_t)k * 512 + h * 64 + c] * av[h * 64 + c];
        wa_t[j * 128 + k] = s;
    }
}

// ---------------- bf16 MFMA GEMM: C[M][N] = A[M][K] @ Bt[N][K]^T ----------------
template <bool AF32, bool BIAS>
__global__ __launch_bounds__(256) void gnn_mfma_gemm(const void* __restrict__ Av,
                                                     const ushort* __restrict__ Bt,
                                                     ushort* __restrict__ C,
                                                     const float* __restrict__ bias,
                                                     int M, int N, int K) {
    __shared__ ushort As[64 * 40];
    __shared__ ushort Bs[64 * 40];
    const int tid = threadIdx.x;
    const int wv = tid >> 6, lane = tid & 63;
    const int g = lane >> 4, r = lane & 15;
    const int brow = blockIdx.y << 6, bcol = blockIdx.x << 6;

    const int srow = tid >> 2;
    const int skoff = (tid & 3) << 3;
    int arow = brow + srow;
    if (arow >= M) arow = M - 1;
    const ushort* A16 = (const ushort*)Av;
    const float*  A32 = (const float*)Av;
    const ushort* Ap16 = A16 + (size_t)arow * K + skoff;
    const float*  Ap32 = A32 + (size_t)arow * K + skoff;
    const ushort* Bp = Bt + (size_t)(bcol + srow) * K + skoff;
    ushort* AsW = &As[srow * 40 + skoff];
    ushort* BsW = &Bs[srow * 40 + skoff];

    f32x4 acc[4] = {};

    for (int k0 = 0; k0 < K; k0 += 32) {
        if constexpr (AF32) {
            float4 f0 = *(const float4*)(Ap32 + k0);
            float4 f1 = *(const float4*)(Ap32 + k0 + 4);
            short8 t;
            t[0] = (short)f2b(f0.x); t[1] = (short)f2b(f0.y);
            t[2] = (short)f2b(f0.z); t[3] = (short)f2b(f0.w);
            t[4] = (short)f2b(f1.x); t[5] = (short)f2b(f1.y);
            t[6] = (short)f2b(f1.z); t[7] = (short)f2b(f1.w);
            *(short8*)AsW = t;
        } else {
            *(short8*)AsW = *(const short8*)(Ap16 + k0);
        }
        *(short8*)BsW = *(const short8*)(Bp + k0);
        __syncthreads();
        short8 bfrag = *(const short8*)&Bs[(wv * 16 + r) * 40 + g * 8];
#pragma unroll
        for (int mb = 0; mb < 4; ++mb) {
            short8 afrag = *(const short8*)&As[(mb * 16 + r) * 40 + g * 8];
            acc[mb] = __builtin_amdgcn_mfma_f32_16x16x32_bf16(afrag, bfrag, acc[mb], 0, 0, 0);
        }
        __syncthreads();
    }

    const int col = bcol + wv * 16 + r;
    float bv = 0.f;
    if constexpr (BIAS) bv = bias[col];
#pragma unroll
    for (int mb = 0; mb < 4; ++mb) {
        int rowb = brow + mb * 16 + g * 4;
#pragma unroll
        for (int rr = 0; rr < 4; ++rr) {
            int row = rowb + rr;
            if (row < M) {
                float val = acc[mb][rr];
                if constexpr (BIAS) {
                    val += bv;
                    val = val > 0.f ? val : 0.f;
                }
                C[(size_t)row * N + col] = f2b(val);
            }
        }
    }
}

// ------- GCN1 gather + bias/relu + fused asd. Half-wave edge pairing. -------
__global__ __launch_bounds__(256) void gnn_gcn_node128_asd(const int* __restrict__ row_ptr,
                                                           const int* __restrict__ esrc,
                                                           const float* __restrict__ ecw,
                                                           const float* __restrict__ dinv,
                                                           const ushort* __restrict__ hb,
                                                           const float* __restrict__ b,
                                                           const float* __restrict__ wa,
                                                           ushort* __restrict__ out,
                                                           float* __restrict__ a_s,
                                                           float* __restrict__ a_d, int n) {
    __shared__ float swa[16 * 128];
    for (int i = threadIdx.x; i < 16 * 128; i += 256) swa[i] = wa[i];
    __syncthreads();
    int v = blockIdx.x * 4 + (threadIdx.x >> 6);
    int lane = threadIdx.x & 63;
    if (v >= n) return;
    const int sl = lane & 31;
    const int half = lane >> 5;
    float di = dinv[v];
    float a0, a1, a2, a3;
    {   // self (half 0 only; half 1 scaled by 0)
        float scl = half ? 0.f : di * di;
        uint2 u = *(const uint2*)(hb + (size_t)v * 128 + 4 * sl);
        a0 = scl * blo(u.x); a1 = scl * bhi(u.x);
        a2 = scl * blo(u.y); a3 = scl * bhi(u.y);
    }
    int beg = row_ptr[v], end = row_ptr[v + 1];
    int cntE = end - beg;
    int pairs = cntE >> 1;
    int i = 0;
    for (; i + 4 <= pairs; i += 4) {
        int s[4]; float c[4]; uint2 u[4];
#pragma unroll
        for (int t = 0; t < 4; ++t) s[t] = esrc[beg + 2 * (i + t) + half];
#pragma unroll
        for (int t = 0; t < 4; ++t) c[t] = ecw[beg + 2 * (i + t) + half];
#pragma unroll
        for (int t = 0; t < 4; ++t) u[t] = *(const uint2*)(hb + (size_t)s[t] * 128 + 4 * sl);
#pragma unroll
        for (int t = 0; t < 4; ++t) {
            a0 += c[t] * blo(u[t].x); a1 += c[t] * bhi(u[t].x);
            a2 += c[t] * blo(u[t].y); a3 += c[t] * bhi(u[t].y);
        }
    }
    for (; i < pairs; ++i) {
        int s = esrc[beg + 2 * i + half];
        float c = ecw[beg + 2 * i + half];
        uint2 u = *(const uint2*)(hb + (size_t)s * 128 + 4 * sl);
        a0 += c * blo(u.x); a1 += c * bhi(u.x);
        a2 += c * blo(u.y); a3 += c * bhi(u.y);
    }
    if (cntE & 1) {  // tail edge: both halves load it, half 1 weight 0
        int s = esrc[end - 1];
        float c = half ? 0.f : ecw[end - 1];
        uint2 u = *(const uint2*)(hb + (size_t)s * 128 + 4 * sl);
        a0 += c * blo(u.x); a1 += c * bhi(u.x);
        a2 += c * blo(u.y); a3 += c * bhi(u.y);
    }
    // fold halves
    a0 += __shfl_xor(a0, 32); a1 += __shfl_xor(a1, 32);
    a2 += __shfl_xor(a2, 32); a3 += __shfl_xor(a3, 32);

    float4 bv = *(const float4*)(b + 4 * sl);
    float o0 = a0 + bv.x, o1 = a1 + bv.y, o2 = a2 + bv.z, o3 = a3 + bv.w;
    o0 = o0 > 0.f ? o0 : 0.f; o1 = o1 > 0.f ? o1 : 0.f;
    o2 = o2 > 0.f ? o2 : 0.f; o3 = o3 > 0.f ? o3 : 0.f;
    if (lane < 32) {
        uint2 w;
        w.x = (uint)f2b(o0) | ((uint)f2b(o1) << 16);
        w.y = (uint)f2b(o2) | ((uint)f2b(o3) << 16);
        *(uint2*)(out + (size_t)v * 128 + 4 * sl) = w;
    }

    // fused a_s/a_d: dot(g1 row, wa[j]); butterfly within 32 (halves identical)
    float part[16];
#pragma unroll
    for (int j = 0; j < 16; ++j) {
        const float* wj = &swa[j * 128 + 4 * sl];
        part[j] = o0 * wj[0] + o1 * wj[1] + o2 * wj[2] + o3 * wj[3];
    }
#pragma unroll
    for (int m = 1; m < 32; m <<= 1) {
#pragma unroll
        for (int j = 0; j < 16; ++j) part[j] += __shfl_xor(part[j], m);
    }
    if (lane == 0) {
#pragma unroll
        for (int j = 0; j < 8; ++j) {
            a_s[(size_t)v * 8 + j] = part[j];
            a_d[(size_t)v * 8 + j] = part[8 + j];
        }
    }
}

// ------- GAT z aggregation, half-wave edge pairing (R10 version) -------
__global__ __launch_bounds__(256) void gnn_gat_z(const int* __restrict__ row_ptr,
                                                 const int* __restrict__ esrc,
                                                 const float* __restrict__ a_s,
                                                 const float* __restrict__ a_d,
                                                 const ushort* __restrict__ g1b,
                                                 ushort* __restrict__ zb, int n) {
    int v = blockIdx.x * 4 + (threadIdx.x >> 6);
    int lane = threadIdx.x & 63;
    if (v >= n) return;
    const int sl = lane & 31;
    const int half = lane >> 5;
    const int hh = lane & 7;
    const int hbase = lane & 32;  // shfl source base for this half
    const float adh = a_d[(size_t)v * 8 + hh];

    float z0[8] = {}, z1[8] = {}, z2[8] = {}, z3[8] = {};
    float sloc = 0.f;
    {   // self edge (half 0 only)
        float pv = __expf(leaky02(a_s[(size_t)v * 8 + hh] + adh));
        if (half) pv = 0.f;
        sloc += pv;
        uint2 u = *(const uint2*)(g1b + (size_t)v * 128 + 4 * sl);
        float g0 = blo(u.x), g1v = bhi(u.x), g2v = blo(u.y), g3v = bhi(u.y);
        float ph[8];
#pragma unroll
        for (int h = 0; h < 8; ++h) ph[h] = __shfl(pv, hbase | h);
#pragma unroll
        for (int h = 0; h < 8; ++h) {
            z0[h] += ph[h] * g0; z1[h] += ph[h] * g1v;
            z2[h] += ph[h] * g2v; z3[h] += ph[h] * g3v;
        }
    }
    int beg = row_ptr[v], end = row_ptr[v + 1];
    int cntE = end - beg;
    int pairs = cntE >> 1;
    int i = 0;
    for (; i + 2 <= pairs; i += 2) {
        int s[2]; float e[2]; uint2 u[2];
#pragma unroll
        for (int t = 0; t < 2; ++t) s[t] = esrc[beg + 2 * (i + t) + half];
#pragma unroll
        for (int t = 0; t < 2; ++t) e[t] = a_s[(size_t)s[t] * 8 + hh];
#pragma unroll
        for (int t = 0; t < 2; ++t) u[t] = *(const uint2*)(g1b + (size_t)s[t] * 128 + 4 * sl);
#pragma unroll
        for (int t = 0; t < 2; ++t) {
            float pv = __expf(leaky02(e[t] + adh));
            sloc += pv;
            float g0 = blo(u[t].x), g1v = bhi(u[t].x), g2v = blo(u[t].y), g3v = bhi(u[t].y);
            float ph[8];
#pragma unroll
            for (int h = 0; h < 8; ++h) ph[h] = __shfl(pv, hbase | h);
#pragma unroll
            for (int h = 0; h < 8; ++h) {
                z0[h] += ph[h] * g0; z1[h] += ph[h] * g1v;
                z2[h] += ph[h] * g2v; z3[h] += ph[h] * g3v;
            }
        }
    }
    for (; i < pairs; ++i) {
        int s = esrc[beg + 2 * i + half];
        float pv = __expf(leaky02(a_s[(size_t)s * 8 + hh] + adh));
        sloc += pv;
        uint2 u = *(const uint2*)(g1b + (size_t)s * 128 + 4 * sl);
        float g0 = blo(u.x), g1v = bhi(u.x), g2v = blo(u.y), g3v = bhi(u.y);
        float ph[8];
#pragma unroll
        for (int h = 0; h < 8; ++h) ph[h] = __shfl(pv, hbase | h);
#pragma unroll
        for (int h = 0; h < 8; ++h) {
            z0[h] += ph[h] * g0; z1[h] += ph[h] * g1v;
            z2[h] += ph[h] * g2v; z3[h] += ph[h] * g3v;
        }
    }
    if (cntE & 1) {
        int s = esrc[end - 1];
        float pv = __expf(leaky02(a_s[(size_t)s * 8 + hh] + adh));
        if (half) pv = 0.f;
        sloc += pv;
        uint2 u = *(const uint2*)(g1b + (size_t)s * 128 + 4 * sl);
        float g0 = blo(u.x), g1v = bhi(u.x), g2v = blo(u.y), g3v = bhi(u.y);
        float ph[8];
#pragma unroll
        for (int h = 0; h < 8; ++h) ph[h] = __shfl(pv, hbase | h);
#pragma unroll
        for (int h = 0; h < 8; ++h) {
            z0[h] += ph[h] * g0; z1[h] += ph[h] * g1v;
            z2[h] += ph[h] * g2v; z3[h] += ph[h] * g3v;
        }
    }
    // fold halves
    float slx = sloc + __shfl_xor(sloc, 32) + 1e-16f;
#pragma unroll
    for (int h = 0; h < 8; ++h) {
        z0[h] += __shfl_xor(z0[h], 32); z1[h] += __shfl_xor(z1[h], 32);
        z2[h] += __shfl_xor(z2[h], 32); z3[h] += __shfl_xor(z3[h], 32);
    }
    if (lane < 32) {
#pragma unroll
        for (int h = 0; h < 8; ++h) {
            float rs = 1.f / __shfl(slx, h);
            uint2 w;
            w.x = (uint)f2b(z0[h] * rs) | ((uint)f2b(z1[h] * rs) << 16);
            w.y = (uint)f2b(z2[h] * rs) | ((uint)f2b(z3[h] * rs) << 16);
            *(uint2*)(zb + (size_t)v * 1024 + h * 128 + 4 * sl) = w;
        }
    }
}

// ---- GCN2 gather + fused FC -> d_out. Half-wave pairing. ----
__global__ __launch_bounds__(256) void gnn_gcn_node64_fc(const int* __restrict__ row_ptr,
                                                         const int* __restrict__ esrc,
                                                         const float* __restrict__ ecw,
                                                         const float* __restrict__ dinv,
                                                         const ushort* __restrict__ hb,
                                                         const float* __restrict__ b,
                                                         const float* __restrict__ fc_w,
                                                         const float* __restrict__ fc_b,
                                                         float* __restrict__ out, int n) {
    int v = blockIdx.x * 4 + (threadIdx.x >> 6);
    int lane = threadIdx.x & 63;
    if (v >= n) return;
    const int sl = lane & 31;
    const int half = lane >> 5;
    float di = dinv[v];
    float a0, a1;
    {
        float scl = half ? 0.f : di * di;
        uint u = *(const uint*)(hb + (size_t)v * 64 + 2 * sl);
        a0 = scl * blo(u); a1 = scl * bhi(u);
    }
    int beg = row_ptr[v], end = row_ptr[v + 1];
    int cntE = end - beg;
    int pairs = cntE >> 1;
    int i = 0;
    for (; i + 4 <= pairs; i += 4) {
        int s[4]; float c[4]; uint u[4];
#pragma unroll
        for (int t = 0; t < 4; ++t) s[t] = esrc[beg + 2 * (i + t) + half];
#pragma unroll
        for (int t = 0; t < 4; ++t) c[t] = ecw[beg + 2 * (i + t) + half];
#pragma unroll
        for (int t = 0; t < 4; ++t) u[t] = *(const uint*)(hb + (size_t)s[t] * 64 + 2 * sl);
#pragma unroll
        for (int t = 0; t < 4; ++t) { a0 += c[t] * blo(u[t]); a1 += c[t] * bhi(u[t]); }
    }
    for (; i < pairs; ++i) {
        int s = esrc[beg + 2 * i + half];
        float c = ecw[beg + 2 * i + half];
        uint u = *(const uint*)(hb + (size_t)s * 64 + 2 * sl);
        a0 += c * blo(u); a1 += c * bhi(u);
    }
    if (cntE & 1) {
        int s = esrc[end - 1];
        float c = half ? 0.f : ecw[end - 1];
        uint u = *(const uint*)(hb + (size_t)s * 64 + 2 * sl);
        a0 += c * blo(u); a1 += c * bhi(u);
    }
    a0 += __shfl_xor(a0, 32);
    a1 += __shfl_xor(a1, 32);
    float o0 = a0 + b[2 * sl];
    float o1 = a1 + b[2 * sl + 1];
    o0 = o0 > 0.f ? o0 : 0.f;
    o1 = o1 > 0.f ? o1 : 0.f;
    float val = o0 * fc_w[2 * sl] + o1 * fc_w[2 * sl + 1];
#pragma unroll
    for (int m = 1; m < 32; m <<= 1) val += __shfl_xor(val, m);
    if (lane == 0) out[v] = val + fc_b[0];
}

// ---------------- launch ----------------
extern "C" void kernel_launch(void* const* d_in, const int* in_sizes, int n_in,
                              void* d_out, int out_size, void* d_ws, size_t ws_size,
                              hipStream_t stream) {
    const float* x       = (const float*)d_in[0];
    const int*   ei      = (const int*)d_in[1];
    const float* ew      = (const float*)d_in[2];
    const float* gc1_w   = (const float*)d_in[3];
    const float* gc1_b   = (const float*)d_in[4];
    const float* gat_w   = (const float*)d_in[5];
    const float* att_src = (const float*)d_in[6];
    const float* att_dst = (const float*)d_in[7];
    const float* gat_b   = (const float*)d_in[8];
    const float* gc2_w   = (const float*)d_in[9];
    const float* gc2_b   = (const float*)d_in[10];
    const float* fc_w    = (const float*)d_in[11];
    const float* fc_b    = (const float*)d_in[12];
    float* out = (float*)d_out;

    const int N = GNN_N;
    const int E = in_sizes[2];
    const int* src = ei;
    const int* dst = ei + E;

    // ---- workspace layout (~153 MB) ----
    char* p = (char*)d_ws;
    ushort* zb  = (ushort*)p; p += (size_t)N * 1024 * 2;  // 102.4 MB [N][8*128] bf16
    ushort* h1b = (ushort*)p; p += (size_t)N * 128 * 2;   // 12.8 MB
    ushort* g1b = (ushort*)p; p += (size_t)N * 128 * 2;   // 12.8 MB
    ushort* g2b = (ushort*)p; p += (size_t)N * 64 * 2;    // 6.4 MB
    ushort* h3b = (ushort*)p; p += (size_t)N * 64 * 2;    // 6.4 MB
    ushort* w1t = (ushort*)p; p += (size_t)128 * 256 * 2; // 64 KB
    ushort* w2s_t = (ushort*)p; p += (size_t)64 * 1024 * 2; // 128 KB
    ushort* w3t = (ushort*)p; p += (size_t)64 * 64 * 2;   // 8 KB
    float*  wa_t = (float*)p; p += 16 * 128 * 4;          // 8 KB
    float*  a_s = (float*)p;  p += (size_t)N * 8 * 4;
    float*  a_d = (float*)p;  p += (size_t)N * 8 * 4;
    int* row_ptr = (int*)p;   p += (size_t)(N + 64) * 4;
    int* esrc = (int*)p;      p += (size_t)E * 4;
    float* ecw = (float*)p;   p += (size_t)E * 4;
    int* tord = (int*)p;      p += (size_t)E * 4;         // 2.4 MB
    int* cnt = (int*)p;       p += (size_t)N * 4;
    int* fill = (int*)p;      p += (size_t)N * 4;
    float* dinv = (float*)p;  p += (size_t)N * 4;
    int* blksum = (int*)p;    p += 4096;

    auto cdiv = [](long a, long b) { return (int)((a + b - 1) / b); };

    // ---- CSR build (deterministic): count -> scan -> scatter idx -> sort rows + deg -> payload
    hipMemsetAsync(cnt, 0, (size_t)N * 8, stream);  // cnt + fill
    gnn_hist<<<cdiv(E, 256), 256, 0, stream>>>(dst, cnt, E);
    const int nblk = cdiv(N, 1024);
    gnn_scan1<<<nblk, 256, 0, stream>>>(cnt, row_ptr, blksum, N);
    gnn_scan2<<<1, 64, 0, stream>>>(blksum, nblk, row_ptr + N, E);
    gnn_scan3<<<cdiv(N, 256), 256, 0, stream>>>(row_ptr, blksum, N);
    gnn_scatter_idx<<<cdiv(E, 256), 256, 0, stream>>>(dst, row_ptr, fill, tord, E);
    gnn_sortdeg<<<cdiv(N, 256), 256, 0, stream>>>(ew, tord, row_ptr, dinv, N);
    gnn_edgefin<<<cdiv(E, 256), 256, 0, stream>>>(src, dst, ew, dinv, tord, esrc, ecw, E);

    // ---- fused prep ----
    gnn_prep<<<408, 256, 0, stream>>>(gc1_w, gat_w, gc2_w, att_src, att_dst, w1t, w2s_t, w3t, wa_t);

    // ---- GCN1: h1b = bf16(x @ gc1_w); gather + fused asd ----
    {
        dim3 grid(128 / 64, cdiv(N, 64));
        gnn_mfma_gemm<true, false><<<grid, 256, 0, stream>>>(x, w1t, h1b, nullptr, N, 128, 256);
    }
    gnn_gcn_node128_asd<<<cdiv(N, 4), 256, 0, stream>>>(row_ptr, esrc, ecw, dinv, h1b, gc1_b,
                                                        wa_t, g1b, a_s, a_d, N);

    // ---- GAT: z-space aggregation then stacked GEMM (bias+relu fused) ----
    gnn_gat_z<<<cdiv(N, 4), 256, 0, stream>>>(row_ptr, esrc, a_s, a_d, g1b, zb, N);
    {
        dim3 grid(1, cdiv(N, 64));
        gnn_mfma_gemm<false, true><<<grid, 256, 0, stream>>>(zb, w2s_t, g2b, gat_b, N, 64, 1024);
    }

    // ---- GCN2 + FC ----
    {
        dim3 grid(1, cdiv(N, 64));
        gnn_mfma_gemm<false, false><<<grid, 256, 0, stream>>>(g2b, w3t, h3b, nullptr, N, 64, 64);
    }
    gnn_gcn_node64_fc<<<cdiv(N, 4), 256, 0, stream>>>(row_ptr, esrc, ecw, dinv, h3b, gc2_b,
                                                      fc_w, fc_b, out, N);
}

// Round 13
// 337.060 us; speedup vs baseline: 1.0779x; 1.0779x over previous
//
#include <hip/hip_runtime.h>
#include <hip/hip_bf16.h>

#define GNN_N 50000
#define GNN_E 600000

typedef unsigned int uint;
typedef unsigned short ushort;
using short8 = __attribute__((ext_vector_type(8))) short;
using f32x4  = __attribute__((ext_vector_type(4))) float;
using f32x2  = __attribute__((ext_vector_type(2))) float;

__device__ __forceinline__ float leaky02(float x) { return x > 0.f ? x : 0.2f * x; }
__device__ __forceinline__ ushort f2b(float f) {  // RNE float->bf16
    uint u = __float_as_uint(f);
    return (ushort)((u + 0x7fffu + ((u >> 16) & 1u)) >> 16);
}
__device__ __forceinline__ float b2f(ushort b) { return __uint_as_float(((uint)b) << 16); }
__device__ __forceinline__ float blo(uint u) { return __uint_as_float(u << 16); }
__device__ __forceinline__ float bhi(uint u) { return __uint_as_float(u & 0xffff0000u); }

// packed dual-fp32 FMA: d = a*b + d (both halves)
__device__ __forceinline__ void pkfma(f32x2& d, f32x2 a, f32x2 b) {
    asm("v_pk_fma_f32 %0, %1, %2, %0" : "+v"(d) : "v"(a), "v"(b));
}
__device__ __forceinline__ f32x2 shfl2(f32x2 x, int srcLane) {
    union { f32x2 f; long long l; } u;
    u.f = x;
    u.l = __shfl(u.l, srcLane);
    return u.f;
}
__device__ __forceinline__ f32x2 shflx2(f32x2 x, int m) {
    union { f32x2 f; long long l; } u;
    u.f = x;
    u.l = __shfl_xor(u.l, m);
    return u.f;
}

// ---------------- CSR build (fully deterministic) ----------------
__global__ void gnn_hist(const int* __restrict__ dst, int* __restrict__ cnt, int e) {
    int i = blockIdx.x * blockDim.x + threadIdx.x;
    if (i < e) atomicAdd(&cnt[dst[i]], 1);
}
__global__ void gnn_scan1(const int* __restrict__ cnt, int* __restrict__ row_ptr,
                          int* __restrict__ blksum, int n) {
    __shared__ int sh[256];
    int tid = threadIdx.x;
    int base = blockIdx.x * 1024 + tid * 4;
    int v0 = (base + 0 < n) ? cnt[base + 0] : 0;
    int v1 = (base + 1 < n) ? cnt[base + 1] : 0;
    int v2 = (base + 2 < n) ? cnt[base + 2] : 0;
    int v3 = (base + 3 < n) ? cnt[base + 3] : 0;
    int tsum = v0 + v1 + v2 + v3;
    sh[tid] = tsum;
    __syncthreads();
    for (int off = 1; off < 256; off <<= 1) {
        int t = (tid >= off) ? sh[tid - off] : 0;
        __syncthreads();
        sh[tid] += t;
        __syncthreads();
    }
    int excl = sh[tid] - tsum;
    if (base + 0 < n) row_ptr[base + 0] = excl; excl += v0;
    if (base + 1 < n) row_ptr[base + 1] = excl; excl += v1;
    if (base + 2 < n) row_ptr[base + 2] = excl; excl += v2;
    if (base + 3 < n) row_ptr[base + 3] = excl;
    if (tid == 255) blksum[blockIdx.x] = sh[255];
}
__global__ void gnn_scan2(int* blksum, int nblk, int* row_ptr_end, int total) {
    if (threadIdx.x == 0 && blockIdx.x == 0) {
        int run = 0;
        for (int b = 0; b < nblk; ++b) { int t = blksum[b]; blksum[b] = run; run += t; }
        *row_ptr_end = total;
    }
}
__global__ void gnn_scan3(int* row_ptr, const int* __restrict__ blksum, int n) {
    int i = blockIdx.x * blockDim.x + threadIdx.x;
    if (i < n) row_ptr[i] += blksum[i >> 10];
}
// place edge indices into rows (slot order arbitrary; canonicalized by gnn_sortdeg)
__global__ void gnn_scatter_idx(const int* __restrict__ dst, const int* __restrict__ row_ptr,
                                int* __restrict__ fill, int* __restrict__ tord, int e) {
    int i = blockIdx.x * blockDim.x + threadIdx.x;
    if (i >= e) return;
    int d = dst[i];
    int pos = row_ptr[d] + atomicAdd(&fill[d], 1);
    tord[pos] = i;
}
// one WAVE per node: bitonic-sort row's edge indices across lanes (canonical order),
// then fixed-tree weighted-degree sum (deterministic) -> dinv.
__global__ __launch_bounds__(256) void gnn_sortdeg(const float* __restrict__ ew,
                                                   int* __restrict__ tord,
                                                   const int* __restrict__ row_ptr,
                                                   float* __restrict__ dinv, int n) {
    int v = blockIdx.x * 4 + (threadIdx.x >> 6);
    int lane = threadIdx.x & 63;
    if (v >= n) return;
    int beg = row_ptr[v], end = row_ptr[v + 1];
    int cnt = end - beg;
    if (cnt <= 64) {
        int val = (lane < cnt) ? tord[beg + lane] : 0x7fffffff;
#pragma unroll
        for (int k = 2; k <= 64; k <<= 1) {
#pragma unroll
            for (int j = k >> 1; j >= 1; j >>= 1) {
                int other = __shfl_xor(val, j);
                bool keepMin = (((lane & j) == 0) == ((lane & k) == 0));
                val = keepMin ? min(val, other) : max(val, other);
            }
        }
        if (lane < cnt) tord[beg + lane] = val;
        float s = (lane < cnt) ? ew[val] : 0.f;
#pragma unroll
        for (int m = 32; m; m >>= 1) s += __shfl_xor(s, m);
        if (lane == 0) dinv[v] = rsqrtf(1.0f + s);
    } else {  // essentially-never fallback, still deterministic
        if (lane == 0) {
            for (int i = beg + 1; i < end; ++i) {
                int key = tord[i];
                int k2 = i - 1;
                while (k2 >= beg && tord[k2] > key) { tord[k2 + 1] = tord[k2]; --k2; }
                tord[k2 + 1] = key;
            }
            float s = 1.f;
            for (int i = beg; i < end; ++i) s += ew[tord[i]];
            dinv[v] = rsqrtf(s);
        }
    }
}
// finalize CSR payload from sorted order (deterministic)
__global__ void gnn_edgefin(const int* __restrict__ src, const int* __restrict__ dst,
                            const float* __restrict__ ew, const float* __restrict__ dinv,
                            const int* __restrict__ tord, int* __restrict__ esrc,
                            float* __restrict__ ecw, int e) {
    int pos = blockIdx.x * blockDim.x + threadIdx.x;
    if (pos >= e) return;
    int i = tord[pos];
    int s = src[i];
    esrc[pos] = s;
    ecw[pos] = dinv[s] * ew[i] * dinv[dst[i]];
}

// ---------------- fused prep: weight transposes/folds ----------------
__global__ void gnn_prep(const float* __restrict__ gc1_w, const float* __restrict__ gat_w,
                         const float* __restrict__ gc2_w, const float* __restrict__ att_src,
                         const float* __restrict__ att_dst, ushort* __restrict__ w1t,
                         ushort* __restrict__ w2s_t, ushort* __restrict__ w3t,
                         float* __restrict__ wa_t) {
    int t = blockIdx.x * 256 + threadIdx.x;
    if (t < 32768) {                       // gc1_w [256][128] -> w1t[128][256]
        int k = t >> 7, n = t & 127;
        w1t[n * 256 + k] = f2b(gc1_w[t]);
        return;
    }
    t -= 32768;
    if (t < 65536) {                       // w2s_t[c][h*128+k] = gat_w[k][h*64+c]/8
        int c = t >> 10, r = t & 1023;
        int h = r >> 7, k = r & 127;
        w2s_t[t] = f2b(0.125f * gat_w[(size_t)k * 512 + h * 64 + c]);
        return;
    }
    t -= 65536;
    if (t < 4096) {                        // gc2_w [64][64] -> w3t[64][64]
        int k = t >> 6, n = t & 63;
        w3t[n * 64 + k] = f2b(gc2_w[t]);
        return;
    }
    t -= 4096;
    if (t < 2048) {                        // wa_t[16][128]: fold att into weight space
        int j = t >> 7, k = t & 127;
        int h = j & 7;
        const float* av = (j < 8) ? att_src : att_dst;
        float s = 0.f;
        for (int c = 0; c < 64; ++c) s += gat_w[(size_t)k * 512 + h * 64 + c] * av[h * 64 + c];
        wa_t[j * 128 + k] = s;
    }
}

// ---------------- bf16 MFMA GEMM: C[M][N] = A[M][K] @ Bt[N][K]^T ----------------
template <bool AF32, bool BIAS>
__global__ __launch_bounds__(256) void gnn_mfma_gemm(const void* __restrict__ Av,
                                                     const ushort* __restrict__ Bt,
                                                     ushort* __restrict__ C,
                                                     const float* __restrict__ bias,
                                                     int M, int N, int K) {
    __shared__ ushort As[64 * 40];
    __shared__ ushort Bs[64 * 40];
    const int tid = threadIdx.x;
    const int wv = tid >> 6, lane = tid & 63;
    const int g = lane >> 4, r = lane & 15;
    const int brow = blockIdx.y << 6, bcol = blockIdx.x << 6;

    const int srow = tid >> 2;
    const int skoff = (tid & 3) << 3;
    int arow = brow + srow;
    if (arow >= M) arow = M - 1;
    const ushort* A16 = (const ushort*)Av;
    const float*  A32 = (const float*)Av;
    const ushort* Ap16 = A16 + (size_t)arow * K + skoff;
    const float*  Ap32 = A32 + (size_t)arow * K + skoff;
    const ushort* Bp = Bt + (size_t)(bcol + srow) * K + skoff;
    ushort* AsW = &As[srow * 40 + skoff];
    ushort* BsW = &Bs[srow * 40 + skoff];

    f32x4 acc[4] = {};

    for (int k0 = 0; k0 < K; k0 += 32) {
        if constexpr (AF32) {
            float4 f0 = *(const float4*)(Ap32 + k0);
            float4 f1 = *(const float4*)(Ap32 + k0 + 4);
            short8 t;
            t[0] = (short)f2b(f0.x); t[1] = (short)f2b(f0.y);
            t[2] = (short)f2b(f0.z); t[3] = (short)f2b(f0.w);
            t[4] = (short)f2b(f1.x); t[5] = (short)f2b(f1.y);
            t[6] = (short)f2b(f1.z); t[7] = (short)f2b(f1.w);
            *(short8*)AsW = t;
        } else {
            *(short8*)AsW = *(const short8*)(Ap16 + k0);
        }
        *(short8*)BsW = *(const short8*)(Bp + k0);
        __syncthreads();
        short8 bfrag = *(const short8*)&Bs[(wv * 16 + r) * 40 + g * 8];
#pragma unroll
        for (int mb = 0; mb < 4; ++mb) {
            short8 afrag = *(const short8*)&As[(mb * 16 + r) * 40 + g * 8];
            acc[mb] = __builtin_amdgcn_mfma_f32_16x16x32_bf16(afrag, bfrag, acc[mb], 0, 0, 0);
        }
        __syncthreads();
    }

    const int col = bcol + wv * 16 + r;
    float bv = 0.f;
    if constexpr (BIAS) bv = bias[col];
#pragma unroll
    for (int mb = 0; mb < 4; ++mb) {
        int rowb = brow + mb * 16 + g * 4;
#pragma unroll
        for (int rr = 0; rr < 4; ++rr) {
            int row = rowb + rr;
            if (row < M) {
                float val = acc[mb][rr];
                if constexpr (BIAS) {
                    val += bv;
                    val = val > 0.f ? val : 0.f;
                }
                C[(size_t)row * N + col] = f2b(val);
            }
        }
    }
}

// ------- GCN1 gather + bias/relu + fused asd. Half-wave edge pairing. -------
__global__ __launch_bounds__(256) void gnn_gcn_node128_asd(const int* __restrict__ row_ptr,
                                                           const int* __restrict__ esrc,
                                                           const float* __restrict__ ecw,
                                                           const float* __restrict__ dinv,
                                                           const ushort* __restrict__ hb,
                                                           const float* __restrict__ b,
                                                           const float* __restrict__ wa,
                                                           ushort* __restrict__ out,
                                                           float* __restrict__ a_s,
                                                           float* __restrict__ a_d, int n) {
    __shared__ float swa[16 * 128];
    for (int i = threadIdx.x; i < 16 * 128; i += 256) swa[i] = wa[i];
    __syncthreads();
    int v = blockIdx.x * 4 + (threadIdx.x >> 6);
    int lane = threadIdx.x & 63;
    if (v >= n) return;
    const int sl = lane & 31;
    const int half = lane >> 5;
    float di = dinv[v];
    float a0, a1, a2, a3;
    {   // self (half 0 only; half 1 scaled by 0)
        float scl = half ? 0.f : di * di;
        uint2 u = *(const uint2*)(hb + (size_t)v * 128 + 4 * sl);
        a0 = scl * blo(u.x); a1 = scl * bhi(u.x);
        a2 = scl * blo(u.y); a3 = scl * bhi(u.y);
    }
    int beg = row_ptr[v], end = row_ptr[v + 1];
    int cntE = end - beg;
    int pairs = cntE >> 1;
    int i = 0;
    for (; i + 4 <= pairs; i += 4) {
        int s[4]; float c[4]; uint2 u[4];
#pragma unroll
        for (int t = 0; t < 4; ++t) s[t] = esrc[beg + 2 * (i + t) + half];
#pragma unroll
        for (int t = 0; t < 4; ++t) c[t] = ecw[beg + 2 * (i + t) + half];
#pragma unroll
        for (int t = 0; t < 4; ++t) u[t] = *(const uint2*)(hb + (size_t)s[t] * 128 + 4 * sl);
#pragma unroll
        for (int t = 0; t < 4; ++t) {
            a0 += c[t] * blo(u[t].x); a1 += c[t] * bhi(u[t].x);
            a2 += c[t] * blo(u[t].y); a3 += c[t] * bhi(u[t].y);
        }
    }
    for (; i < pairs; ++i) {
        int s = esrc[beg + 2 * i + half];
        float c = ecw[beg + 2 * i + half];
        uint2 u = *(const uint2*)(hb + (size_t)s * 128 + 4 * sl);
        a0 += c * blo(u.x); a1 += c * bhi(u.x);
        a2 += c * blo(u.y); a3 += c * bhi(u.y);
    }
    if (cntE & 1) {  // tail edge: both halves load it, half 1 weight 0
        int s = esrc[end - 1];
        float c = half ? 0.f : ecw[end - 1];
        uint2 u = *(const uint2*)(hb + (size_t)s * 128 + 4 * sl);
        a0 += c * blo(u.x); a1 += c * bhi(u.x);
        a2 += c * blo(u.y); a3 += c * bhi(u.y);
    }
    // fold halves
    a0 += __shfl_xor(a0, 32); a1 += __shfl_xor(a1, 32);
    a2 += __shfl_xor(a2, 32); a3 += __shfl_xor(a3, 32);

    float4 bv = *(const float4*)(b + 4 * sl);
    float o0 = a0 + bv.x, o1 = a1 + bv.y, o2 = a2 + bv.z, o3 = a3 + bv.w;
    o0 = o0 > 0.f ? o0 : 0.f; o1 = o1 > 0.f ? o1 : 0.f;
    o2 = o2 > 0.f ? o2 : 0.f; o3 = o3 > 0.f ? o3 : 0.f;
    if (lane < 32) {
        uint2 w;
        w.x = (uint)f2b(o0) | ((uint)f2b(o1) << 16);
        w.y = (uint)f2b(o2) | ((uint)f2b(o3) << 16);
        *(uint2*)(out + (size_t)v * 128 + 4 * sl) = w;
    }

    // fused a_s/a_d: dot(g1 row, wa[j]); butterfly within 32 (halves identical)
    float part[16];
#pragma unroll
    for (int j = 0; j < 16; ++j) {
        const float* wj = &swa[j * 128 + 4 * sl];
        part[j] = o0 * wj[0] + o1 * wj[1] + o2 * wj[2] + o3 * wj[3];
    }
#pragma unroll
    for (int m = 1; m < 32; m <<= 1) {
#pragma unroll
        for (int j = 0; j < 16; ++j) part[j] += __shfl_xor(part[j], m);
    }
    if (lane == 0) {
#pragma unroll
        for (int j = 0; j < 8; ++j) {
            a_s[(size_t)v * 8 + j] = part[j];
            a_d[(size_t)v * 8 + j] = part[8 + j];
        }
    }
}

// ------- GAT z aggregation, half-wave edge pairing + packed fp32 FMA -------
__global__ __launch_bounds__(256) void gnn_gat_z(const int* __restrict__ row_ptr,
                                                 const int* __restrict__ esrc,
                                                 const float* __restrict__ a_s,
                                                 const float* __restrict__ a_d,
                                                 const ushort* __restrict__ g1b,
                                                 ushort* __restrict__ zb, int n) {
    int v = blockIdx.x * 4 + (threadIdx.x >> 6);
    int lane = threadIdx.x & 63;
    if (v >= n) return;
    const int sl = lane & 31;
    const int half = lane >> 5;
    const int hh = lane & 7;
    const int hbase = lane & 32;  // shfl source base for this half
    const float adh = a_d[(size_t)v * 8 + hh];

    f32x2 zA[8] = {}, zB[8] = {};
    float sloc = 0.f;
    {   // self edge (half 0 only)
        float pv = __expf(leaky02(a_s[(size_t)v * 8 + hh] + adh));
        if (half) pv = 0.f;
        sloc += pv;
        f32x2 pv2; pv2[0] = pv; pv2[1] = pv;
        uint2 u = *(const uint2*)(g1b + (size_t)v * 128 + 4 * sl);
        f32x2 gA; gA[0] = blo(u.x); gA[1] = bhi(u.x);
        f32x2 gB; gB[0] = blo(u.y); gB[1] = bhi(u.y);
#pragma unroll
        for (int h = 0; h < 8; ++h) {
            f32x2 ph2 = shfl2(pv2, hbase | h);
            pkfma(zA[h], gA, ph2);
            pkfma(zB[h], gB, ph2);
        }
    }
    int beg = row_ptr[v], end = row_ptr[v + 1];
    int cntE = end - beg;
    int pairs = cntE >> 1;
    int i = 0;
    for (; i + 2 <= pairs; i += 2) {
        int s[2]; float e[2]; uint2 u[2];
#pragma unroll
        for (int t = 0; t < 2; ++t) s[t] = esrc[beg + 2 * (i + t) + half];
#pragma unroll
        for (int t = 0; t < 2; ++t) e[t] = a_s[(size_t)s[t] * 8 + hh];
#pragma unroll
        for (int t = 0; t < 2; ++t) u[t] = *(const uint2*)(g1b + (size_t)s[t] * 128 + 4 * sl);
#pragma unroll
        for (int t = 0; t < 2; ++t) {
            float pv = __expf(leaky02(e[t] + adh));
            sloc += pv;
            f32x2 pv2; pv2[0] = pv; pv2[1] = pv;
            f32x2 gA; gA[0] = blo(u[t].x); gA[1] = bhi(u[t].x);
            f32x2 gB; gB[0] = blo(u[t].y); gB[1] = bhi(u[t].y);
#pragma unroll
            for (int h = 0; h < 8; ++h) {
                f32x2 ph2 = shfl2(pv2, hbase | h);
                pkfma(zA[h], gA, ph2);
                pkfma(zB[h], gB, ph2);
            }
        }
    }
    for (; i < pairs; ++i) {
        int s = esrc[beg + 2 * i + half];
        float pv = __expf(leaky02(a_s[(size_t)s * 8 + hh] + adh));
        sloc += pv;
        f32x2 pv2; pv2[0] = pv; pv2[1] = pv;
        uint2 u = *(const uint2*)(g1b + (size_t)s * 128 + 4 * sl);
        f32x2 gA; gA[0] = blo(u.x); gA[1] = bhi(u.x);
        f32x2 gB; gB[0] = blo(u.y); gB[1] = bhi(u.y);
#pragma unroll
        for (int h = 0; h < 8; ++h) {
            f32x2 ph2 = shfl2(pv2, hbase | h);
            pkfma(zA[h], gA, ph2);
            pkfma(zB[h], gB, ph2);
        }
    }
    if (cntE & 1) {
        int s = esrc[end - 1];
        float pv = __expf(leaky02(a_s[(size_t)s * 8 + hh] + adh));
        if (half) pv = 0.f;
        sloc += pv;
        f32x2 pv2; pv2[0] = pv; pv2[1] = pv;
        uint2 u = *(const uint2*)(g1b + (size_t)s * 128 + 4 * sl);
        f32x2 gA; gA[0] = blo(u.x); gA[1] = bhi(u.x);
        f32x2 gB; gB[0] = blo(u.y); gB[1] = bhi(u.y);
#pragma unroll
        for (int h = 0; h < 8; ++h) {
            f32x2 ph2 = shfl2(pv2, hbase | h);
            pkfma(zA[h], gA, ph2);
            pkfma(zB[h], gB, ph2);
        }
    }
    // fold halves
    float slx = sloc + __shfl_xor(sloc, 32) + 1e-16f;
#pragma unroll
    for (int h = 0; h < 8; ++h) {
        zA[h] = zA[h] + shflx2(zA[h], 32);
        zB[h] = zB[h] + shflx2(zB[h], 32);
    }
    if (lane < 32) {
#pragma unroll
        for (int h = 0; h < 8; ++h) {
            float rs = 1.f / __shfl(slx, h);
            uint2 w;
            w.x = (uint)f2b(zA[h][0] * rs) | ((uint)f2b(zA[h][1] * rs) << 16);
            w.y = (uint)f2b(zB[h][0] * rs) | ((uint)f2b(zB[h][1] * rs) << 16);
            *(uint2*)(zb + (size_t)v * 1024 + h * 128 + 4 * sl) = w;
        }
    }
}

// ---- GCN2 gather + fused FC -> d_out. Half-wave pairing. ----
__global__ __launch_bounds__(256) void gnn_gcn_node64_fc(const int* __restrict__ row_ptr,
                                                         const int* __restrict__ esrc,
                                                         const float* __restrict__ ecw,
                                                         const float* __restrict__ dinv,
                                                         const ushort* __restrict__ hb,
                                                         const float* __restrict__ b,
                                                         const float* __restrict__ fc_w,
                                                         const float* __restrict__ fc_b,
                                                         float* __restrict__ out, int n) {
    int v = blockIdx.x * 4 + (threadIdx.x >> 6);
    int lane = threadIdx.x & 63;
    if (v >= n) return;
    const int sl = lane & 31;
    const int half = lane >> 5;
    float di = dinv[v];
    float a0, a1;
    {
        float scl = half ? 0.f : di * di;
        uint u = *(const uint*)(hb + (size_t)v * 64 + 2 * sl);
        a0 = scl * blo(u); a1 = scl * bhi(u);
    }
    int beg = row_ptr[v], end = row_ptr[v + 1];
    int cntE = end - beg;
    int pairs = cntE >> 1;
    int i = 0;
    for (; i + 4 <= pairs; i += 4) {
        int s[4]; float c[4]; uint u[4];
#pragma unroll
        for (int t = 0; t < 4; ++t) s[t] = esrc[beg + 2 * (i + t) + half];
#pragma unroll
        for (int t = 0; t < 4; ++t) c[t] = ecw[beg + 2 * (i + t) + half];
#pragma unroll
        for (int t = 0; t < 4; ++t) u[t] = *(const uint*)(hb + (size_t)s[t] * 64 + 2 * sl);
#pragma unroll
        for (int t = 0; t < 4; ++t) { a0 += c[t] * blo(u[t]); a1 += c[t] * bhi(u[t]); }
    }
    for (; i < pairs; ++i) {
        int s = esrc[beg + 2 * i + half];
        float c = ecw[beg + 2 * i + half];
        uint u = *(const uint*)(hb + (size_t)s * 64 + 2 * sl);
        a0 += c * blo(u); a1 += c * bhi(u);
    }
    if (cntE & 1) {
        int s = esrc[end - 1];
        float c = half ? 0.f : ecw[end - 1];
        uint u = *(const uint*)(hb + (size_t)s * 64 + 2 * sl);
        a0 += c * blo(u); a1 += c * bhi(u);
    }
    a0 += __shfl_xor(a0, 32);
    a1 += __shfl_xor(a1, 32);
    float o0 = a0 + b[2 * sl];
    float o1 = a1 + b[2 * sl + 1];
    o0 = o0 > 0.f ? o0 : 0.f;
    o1 = o1 > 0.f ? o1 : 0.f;
    float val = o0 * fc_w[2 * sl] + o1 * fc_w[2 * sl + 1];
#pragma unroll
    for (int m = 1; m < 32; m <<= 1) val += __shfl_xor(val, m);
    if (lane == 0) out[v] = val + fc_b[0];
}

// ---------------- launch ----------------
extern "C" void kernel_launch(void* const* d_in, const int* in_sizes, int n_in,
                              void* d_out, int out_size, void* d_ws, size_t ws_size,
                              hipStream_t stream) {
    const float* x       = (const float*)d_in[0];
    const int*   ei      = (const int*)d_in[1];
    const float* ew      = (const float*)d_in[2];
    const float* gc1_w   = (const float*)d_in[3];
    const float* gc1_b   = (const float*)d_in[4];
    const float* gat_w   = (const float*)d_in[5];
    const float* att_src = (const float*)d_in[6];
    const float* att_dst = (const float*)d_in[7];
    const float* gat_b   = (const float*)d_in[8];
    const float* gc2_w   = (const float*)d_in[9];
    const float* gc2_b   = (const float*)d_in[10];
    const float* fc_w    = (const float*)d_in[11];
    const float* fc_b    = (const float*)d_in[12];
    float* out = (float*)d_out;

    const int N = GNN_N;
    const int E = in_sizes[2];
    const int* src = ei;
    const int* dst = ei + E;

    // ---- workspace layout (~153 MB) ----
    char* p = (char*)d_ws;
    ushort* zb  = (ushort*)p; p += (size_t)N * 1024 * 2;  // 102.4 MB [N][8*128] bf16
    ushort* h1b = (ushort*)p; p += (size_t)N * 128 * 2;   // 12.8 MB
    ushort* g1b = (ushort*)p; p += (size_t)N * 128 * 2;   // 12.8 MB
    ushort* g2b = (ushort*)p; p += (size_t)N * 64 * 2;    // 6.4 MB
    ushort* h3b = (ushort*)p; p += (size_t)N * 64 * 2;    // 6.4 MB
    ushort* w1t = (ushort*)p; p += (size_t)128 * 256 * 2; // 64 KB
    ushort* w2s_t = (ushort*)p; p += (size_t)64 * 1024 * 2; // 128 KB
    ushort* w3t = (ushort*)p; p += (size_t)64 * 64 * 2;   // 8 KB
    float*  wa_t = (float*)p; p += 16 * 128 * 4;          // 8 KB
    float*  a_s = (float*)p;  p += (size_t)N * 8 * 4;
    float*  a_d = (float*)p;  p += (size_t)N * 8 * 4;
    int* row_ptr = (int*)p;   p += (size_t)(N + 64) * 4;
    int* esrc = (int*)p;      p += (size_t)E * 4;
    float* ecw = (float*)p;   p += (size_t)E * 4;
    int* tord = (int*)p;      p += (size_t)E * 4;         // 2.4 MB
    int* cnt = (int*)p;       p += (size_t)N * 4;
    int* fill = (int*)p;      p += (size_t)N * 4;
    float* dinv = (float*)p;  p += (size_t)N * 4;
    int* blksum = (int*)p;    p += 4096;

    auto cdiv = [](long a, long b) { return (int)((a + b - 1) / b); };

    // ---- CSR build (deterministic): count -> scan -> scatter idx -> wave-sort + deg -> payload
    hipMemsetAsync(cnt, 0, (size_t)N * 8, stream);  // cnt + fill
    gnn_hist<<<cdiv(E, 256), 256, 0, stream>>>(dst, cnt, E);
    const int nblk = cdiv(N, 1024);
    gnn_scan1<<<nblk, 256, 0, stream>>>(cnt, row_ptr, blksum, N);
    gnn_scan2<<<1, 64, 0, stream>>>(blksum, nblk, row_ptr + N, E);
    gnn_scan3<<<cdiv(N, 256), 256, 0, stream>>>(row_ptr, blksum, N);
    gnn_scatter_idx<<<cdiv(E, 256), 256, 0, stream>>>(dst, row_ptr, fill, tord, E);
    gnn_sortdeg<<<cdiv(N, 4), 256, 0, stream>>>(ew, tord, row_ptr, dinv, N);
    gnn_edgefin<<<cdiv(E, 256), 256, 0, stream>>>(src, dst, ew, dinv, tord, esrc, ecw, E);

    // ---- fused prep ----
    gnn_prep<<<408, 256, 0, stream>>>(gc1_w, gat_w, gc2_w, att_src, att_dst, w1t, w2s_t, w3t, wa_t);

    // ---- GCN1: h1b = bf16(x @ gc1_w); gather + fused asd ----
    {
        dim3 grid(128 / 64, cdiv(N, 64));
        gnn_mfma_gemm<true, false><<<grid, 256, 0, stream>>>(x, w1t, h1b, nullptr, N, 128, 256);
    }
    gnn_gcn_node128_asd<<<cdiv(N, 4), 256, 0, stream>>>(row_ptr, esrc, ecw, dinv, h1b, gc1_b,
                                                        wa_t, g1b, a_s, a_d, N);

    // ---- GAT: z-space aggregation then stacked GEMM (bias+relu fused) ----
    gnn_gat_z<<<cdiv(N, 4), 256, 0, stream>>>(row_ptr, esrc, a_s, a_d, g1b, zb, N);
    {
        dim3 grid(1, cdiv(N, 64));
        gnn_mfma_gemm<false, true><<<grid, 256, 0, stream>>>(zb, w2s_t, g2b, gat_b, N, 64, 1024);
    }

    // ---- GCN2 + FC ----
    {
        dim3 grid(1, cdiv(N, 64));
        gnn_mfma_gemm<false, false><<<grid, 256, 0, stream>>>(g2b, w3t, h3b, nullptr, N, 64, 64);
    }
    gnn_gcn_node64_fc<<<cdiv(N, 4), 256, 0, stream>>>(row_ptr, esrc, ecw, dinv, h3b, gc2_b,
                                                      fc_w, fc_b, out, N);
}